// Round 18
// baseline (280.097 us; speedup 1.0000x reference)
//
#include <hip/hip_runtime.h>
#include <hip/hip_bf16.h>

typedef float    f32x4 __attribute__((ext_vector_type(4)));
typedef short    s16x8 __attribute__((ext_vector_type(8)));
typedef unsigned u32x4 __attribute__((ext_vector_type(4)));

__device__ __forceinline__ unsigned short f2bf(float f) {
    union { __hip_bfloat16 b; unsigned short u; } v;
    v.b = __float2bfloat16(f);
    return v.u;
}
// HW packed f32->bf16 (RTNE, same as __float2bfloat16): 2 converts / 1 op.
__device__ __forceinline__ unsigned cvtpk(float lo, float hi) {
    unsigned r;
    asm("v_cvt_pk_bf16_f32 %0, %1, %2" : "=v"(r) : "v"(lo), "v"(hi));
    return r;
}
__device__ __forceinline__ float sigf(float x)  {
    return __builtin_amdgcn_rcpf(1.0f + __expf(-x));
}

__device__ __forceinline__ s16x8 pack8(float4 a, float4 b) {
    union { u32x4 u; s16x8 v; } r;
    r.u[0] = cvtpk(a.x, a.y);
    r.u[1] = cvtpk(a.z, a.w);
    r.u[2] = cvtpk(b.x, b.y);
    r.u[3] = cvtpk(b.z, b.w);
    return r.v;
}

// ---------------------------------------------------------------------------
// Kernel 1: convert atom_fea fp32 -> bf16, rows PERMUTED into B-fragment
// split-half order: Af[a][(kh*4+q)*8 + jj] = bf16(atom[a][kh*32 + q*4 +
// (jj&3) + (jj>=4 ? 16 : 0)]).  Each lane's fragment = one 16 B load.
// ---------------------------------------------------------------------------
__global__ __launch_bounds__(256) void atom_conv_kernel(
    const float* __restrict__ atom_fea, unsigned short* __restrict__ Af, int total)
{
    int i = blockIdx.x * blockDim.x + threadIdx.x;
    const int stride = gridDim.x * blockDim.x;
    for (; i < total; i += stride) {
        int a = i >> 6, p = i & 63;
        int kh = p >> 5, q = (p >> 3) & 3, jj = p & 7;
        int k = kh * 32 + q * 4 + (jj & 3) + ((jj & 4) ? 16 : 0);
        Af[i] = f2bf(atom_fea[(size_t)a * 64 + k]);
    }
}

// ---------------------------------------------------------------------------
// Helpers for the edge kernel (fully inlined; all indices compile-time).
// ---------------------------------------------------------------------------
__device__ __forceinline__ void layer1_atom(
    const unsigned short* wlds, int lane,
    s16x8 ai0, s16x8 ai1, s16x8 aj0, s16x8 aj1,
    f32x4 acc1[4], f32x4 acc2[4])
{
    #pragma unroll
    for (int nb = 0; nb < 4; ++nb) {
        s16x8 w;
        w = *(const s16x8*)&wlds[( 0 + nb) * 512 + lane * 8];
        acc1[nb] = __builtin_amdgcn_mfma_f32_16x16x32_bf16(w, ai0, acc1[nb], 0, 0, 0);
        w = *(const s16x8*)&wlds[( 4 + nb) * 512 + lane * 8];
        acc1[nb] = __builtin_amdgcn_mfma_f32_16x16x32_bf16(w, ai1, acc1[nb], 0, 0, 0);
        w = *(const s16x8*)&wlds[( 8 + nb) * 512 + lane * 8];
        acc1[nb] = __builtin_amdgcn_mfma_f32_16x16x32_bf16(w, aj0, acc1[nb], 0, 0, 0);
        w = *(const s16x8*)&wlds[(12 + nb) * 512 + lane * 8];
        acc1[nb] = __builtin_amdgcn_mfma_f32_16x16x32_bf16(w, aj1, acc1[nb], 0, 0, 0);
        w = *(const s16x8*)&wlds[(24 + nb) * 512 + lane * 8];
        acc2[nb] = __builtin_amdgcn_mfma_f32_16x16x32_bf16(w, ai0, acc2[nb], 0, 0, 0);
        w = *(const s16x8*)&wlds[(28 + nb) * 512 + lane * 8];
        acc2[nb] = __builtin_amdgcn_mfma_f32_16x16x32_bf16(w, ai1, acc2[nb], 0, 0, 0);
        w = *(const s16x8*)&wlds[(32 + nb) * 512 + lane * 8];
        acc2[nb] = __builtin_amdgcn_mfma_f32_16x16x32_bf16(w, aj0, acc2[nb], 0, 0, 0);
        w = *(const s16x8*)&wlds[(36 + nb) * 512 + lane * 8];
        acc2[nb] = __builtin_amdgcn_mfma_f32_16x16x32_bf16(w, aj1, acc2[nb], 0, 0, 0);
    }
}

__device__ __forceinline__ void layer1_eij(
    const unsigned short* wlds, int lane,
    s16x8 xf0, s16x8 xf1, f32x4 acc1[4], f32x4 acc2[4])
{
    #pragma unroll
    for (int nb = 0; nb < 4; ++nb) {
        s16x8 w;
        w = *(const s16x8*)&wlds[(16 + nb) * 512 + lane * 8];
        acc1[nb] = __builtin_amdgcn_mfma_f32_16x16x32_bf16(w, xf0, acc1[nb], 0, 0, 0);
        w = *(const s16x8*)&wlds[(20 + nb) * 512 + lane * 8];
        acc1[nb] = __builtin_amdgcn_mfma_f32_16x16x32_bf16(w, xf1, acc1[nb], 0, 0, 0);
        w = *(const s16x8*)&wlds[(40 + nb) * 512 + lane * 8];
        acc2[nb] = __builtin_amdgcn_mfma_f32_16x16x32_bf16(w, xf0, acc2[nb], 0, 0, 0);
        w = *(const s16x8*)&wlds[(44 + nb) * 512 + lane * 8];
        acc2[nb] = __builtin_amdgcn_mfma_f32_16x16x32_bf16(w, xf1, acc2[nb], 0, 0, 0);
    }
}

// h -> layer2 -> gate -> store for one 16-edge tile (rows row0 + q*4 + j)
__device__ __forceinline__ void finish_tile(
    f32x4 acc1[4], f32x4 acc2[4], float4 rb,
    const s16x8 w3f[8], const s16x8 wrf[4], const float* blds,
    float* __restrict__ out, int row0, int n_edges, int q, int n)
{
    s16x8 bfrag;
    {
        union { u32x4 u; s16x8 v; } B;
        B.u[0] = cvtpk(rb.x, rb.y);
        B.u[1] = cvtpk(rb.z, rb.w);
        B.u[2] = 0; B.u[3] = 0;
        bfrag = B.v;
    }
    f32x4 h[4];
    #pragma unroll
    for (int nb = 0; nb < 4; ++nb) {
        f32x4 s1 = acc1[nb], s2 = acc2[nb], hv;
        #pragma unroll
        for (int j = 0; j < 4; ++j)
            hv[j] = s1[j] * sigf(s1[j]) * sigf(s2[j]);
        h[nb] = hv;
    }
    s16x8 hf0, hf1;
    {
        union { u32x4 u; s16x8 v; } H0, H1;
        H0.u[0] = cvtpk(h[0][0], h[0][1]);
        H0.u[1] = cvtpk(h[0][2], h[0][3]);
        H0.u[2] = cvtpk(h[1][0], h[1][1]);
        H0.u[3] = cvtpk(h[1][2], h[1][3]);
        H1.u[0] = cvtpk(h[2][0], h[2][1]);
        H1.u[1] = cvtpk(h[2][2], h[2][3]);
        H1.u[2] = cvtpk(h[3][0], h[3][1]);
        H1.u[3] = cvtpk(h[3][2], h[3][3]);
        hf0 = H0.v; hf1 = H1.v;
    }
    f32x4 a3[4], g[4];
    #pragma unroll
    for (int nb = 0; nb < 4; ++nb) { a3[nb] = (f32x4){0,0,0,0}; g[nb] = (f32x4){0,0,0,0}; }
    #pragma unroll
    for (int nb = 0; nb < 4; ++nb) {
        a3[nb] = __builtin_amdgcn_mfma_f32_16x16x32_bf16(hf0, w3f[nb],     a3[nb], 0, 0, 0);
        a3[nb] = __builtin_amdgcn_mfma_f32_16x16x32_bf16(hf1, w3f[4 + nb], a3[nb], 0, 0, 0);
        g[nb]  = __builtin_amdgcn_mfma_f32_16x16x32_bf16(bfrag, wrf[nb],   g[nb],  0, 0, 0);
    }
    float* outp = out + (size_t)(row0 + q * 4) * 64 + n;
    if (row0 + 16 <= n_edges) {
        #pragma unroll
        for (int nb = 0; nb < 4; ++nb) {
            const float b3s = blds[128 + nb * 16 + n];
            const float brs = blds[192 + nb * 16 + n];
            f32x4 s  = a3[nb] + b3s;
            f32x4 gg = g[nb] + brs;
            f32x4 o;
            #pragma unroll
            for (int j = 0; j < 4; ++j)
                o[j] = s[j] * sigf(s[j]) * gg[j];
            #pragma unroll
            for (int j = 0; j < 4; ++j)
                outp[j * 64 + nb * 16] = o[j];
        }
    } else {
        #pragma unroll
        for (int nb = 0; nb < 4; ++nb) {
            const float b3s = blds[128 + nb * 16 + n];
            const float brs = blds[192 + nb * 16 + n];
            f32x4 s  = a3[nb] + b3s;
            f32x4 gg = g[nb] + brs;
            #pragma unroll
            for (int j = 0; j < 4; ++j)
                if (row0 + q * 4 + j < n_edges)
                    outp[j * 64 + nb * 16] = s[j] * sigf(s[j]) * gg[j];
        }
    }
}

// ---------------------------------------------------------------------------
// Kernel 2: MFMA edge kernel. R18: TWO adjacent 16-edge tiles per wave
// iteration (32 edges) — tile B's independent MFMA/VALU stream fills tile
// A's dependency stalls (occupancy is pinned at 2 blocks/CU regardless of
// LDS per R14/R17, so ILP-in-wave is the remaining latency lever; VGPR up
// to 256 is free at 2 waves/SIMD). W2-e_ij back in LDS (R17's reg move
// bought nothing). NCH=48, W3/Wr in regs (R16 config, best at 256 us).
// Spill check: WRITE == 400.0 MB.
// ---------------------------------------------------------------------------
#define NCH 48

__global__ __launch_bounds__(256, 1) void edge_kernel(
    const unsigned short* __restrict__ Af,
    const float* __restrict__ edge_ij,
    const int*   __restrict__ nbr,
    const float* __restrict__ bonds_r,
    const float* __restrict__ W1, const float* __restrict__ b1,
    const float* __restrict__ W2, const float* __restrict__ b2,
    const float* __restrict__ W3, const float* __restrict__ b3,
    const float* __restrict__ Wr, const float* __restrict__ br,
    float* __restrict__ out, int n_edges)
{
    __shared__ unsigned short wlds[NCH * 512];   // 48 KiB: W1 + W2 fragments
    __shared__ float blds[256];                  // b1 | b2 | b3 | br

    const int t    = threadIdx.x;
    const int wave = t >> 6;
    const int lane = t & 63;
    const int q    = lane >> 4;
    const int n    = lane & 15;

    // ---- stage W1/W2 fragments (R16 layout) ----
    for (int ch = 0; ch < NCH; ++ch) {
        int idx = t * 2;
        #pragma unroll
        for (int e2 = 0; e2 < 2; ++e2, ++idx) {
            const int l  = idx >> 3, j = idx & 7;
            const int lq = l >> 4, ln = l & 15;
            const int kk = (j < 4) ? (lq * 4 + j) : (16 + lq * 4 + (j - 4));
            float val;
            if (ch < 24) {
                int kh = ch >> 2, nb = ch & 3;
                val = W1[(size_t)(kh * 32 + kk) * 64 + nb * 16 + ln];
            } else {
                int c2 = ch - 24; int kh = c2 >> 2, nb = c2 & 3;
                val = W2[(size_t)(kh * 32 + kk) * 64 + nb * 16 + ln];
            }
            wlds[ch * 512 + idx] = f2bf(val);
        }
    }
    if (t < 64)        blds[t] = b1[t];
    else if (t < 128)  blds[t] = b2[t - 64];
    else if (t < 192)  blds[t] = b3[t - 128];
    else               blds[t] = br[t - 192];

    // ---- W3/Wr fragments persistent in registers ----
    s16x8 w3f[8], wrf[4];
    {
        const int ln = lane & 15;
        const int lq = lane >> 4;
        #pragma unroll
        for (int c2 = 0; c2 < 8; ++c2) {
            const int kh = c2 >> 2, nb = c2 & 3;
            s16x8 w;
            #pragma unroll
            for (int j = 0; j < 8; ++j) {
                const int kk = (j < 4) ? (lq * 4 + j) : (16 + lq * 4 + (j - 4));
                w[j] = (short)f2bf(W3[(size_t)(kh * 32 + kk) * 64 + nb * 16 + ln]);
            }
            w3f[c2] = w;
        }
        #pragma unroll
        for (int nb = 0; nb < 4; ++nb) {
            s16x8 w;
            #pragma unroll
            for (int j = 0; j < 8; ++j) {
                const int kk = (j < 4) ? (lq * 4 + j) : (16 + lq * 4 + (j - 4));
                w[j] = (short)(kk < 16 ? f2bf(Wr[(size_t)kk * 64 + nb * 16 + ln]) : 0);
            }
            wrf[nb] = w;
        }
    }
    __syncthreads();

    const int pairs   = (n_edges + 31) >> 5;     // 32 edges per iteration
    const int tstride = gridDim.x * 4;
    int P = blockIdx.x * 4 + wave;
    if (P >= pairs) return;

    const int2* nb2 = (const int2*)nbr;

    // ---- prologue: load pair P operands + next-pair indices ----
    int2 nbcA = nb2[min(P * 32 + n,      n_edges - 1)];
    int2 nbcB = nb2[min(P * 32 + 16 + n, n_edges - 1)];
    int Pn = P + tstride;
    bool havenext = (Pn < pairs);
    int2 nbnA = nbcA, nbnB = nbcB;
    if (havenext) {
        nbnA = nb2[min(Pn * 32 + n,      n_edges - 1)];
        nbnB = nb2[min(Pn * 32 + 16 + n, n_edges - 1)];
    }

    const int eA = min(P * 32 + n,      n_edges - 1);
    const int eB = min(P * 32 + 16 + n, n_edges - 1);
    s16x8 aiA0 = *(const s16x8*)&Af[(size_t)nbcA.x * 64 + q * 8];
    s16x8 aiA1 = *(const s16x8*)&Af[(size_t)nbcA.x * 64 + 32 + q * 8];
    s16x8 ajA0 = *(const s16x8*)&Af[(size_t)nbcA.y * 64 + q * 8];
    s16x8 ajA1 = *(const s16x8*)&Af[(size_t)nbcA.y * 64 + 32 + q * 8];
    s16x8 aiB0 = *(const s16x8*)&Af[(size_t)nbcB.x * 64 + q * 8];
    s16x8 aiB1 = *(const s16x8*)&Af[(size_t)nbcB.x * 64 + 32 + q * 8];
    s16x8 ajB0 = *(const s16x8*)&Af[(size_t)nbcB.y * 64 + q * 8];
    s16x8 ajB1 = *(const s16x8*)&Af[(size_t)nbcB.y * 64 + 32 + q * 8];
    const float* xrA = edge_ij + (size_t)eA * 64;
    const float* xrB = edge_ij + (size_t)eB * 64;
    float4 rxA0 = *(const float4*)(xrA +      q * 4);
    float4 rxA1 = *(const float4*)(xrA + 16 + q * 4);
    float4 rxA2 = *(const float4*)(xrA + 32 + q * 4);
    float4 rxA3 = *(const float4*)(xrA + 48 + q * 4);
    float4 rxB0 = *(const float4*)(xrB +      q * 4);
    float4 rxB1 = *(const float4*)(xrB + 16 + q * 4);
    float4 rxB2 = *(const float4*)(xrB + 32 + q * 4);
    float4 rxB3 = *(const float4*)(xrB + 48 + q * 4);
    float4 rbA  = *(const float4*)(bonds_r + (size_t)eA * 16 + q * 4);
    float4 rbB  = *(const float4*)(bonds_r + (size_t)eB * 16 + q * 4);

    while (true) {
        const int E0 = P * 32;

        // ---- pack both tiles' e_ij to bf16 (frees 40 float regs) ----
        s16x8 xfA0 = pack8(rxA0, rxA1);
        s16x8 xfA1 = pack8(rxA2, rxA3);
        s16x8 xfB0 = pack8(rxB0, rxB1);
        s16x8 xfB1 = pack8(rxB2, rxB3);

        // ---- acc init + layer-1 atom MFMAs, tiles A then B ----
        f32x4 acc1A[4], acc2A[4], acc1B[4], acc2B[4];
        #pragma unroll
        for (int nb = 0; nb < 4; ++nb) {
            acc1A[nb] = *(const f32x4*)&blds[nb * 16 + q * 4];
            acc2A[nb] = *(const f32x4*)&blds[64 + nb * 16 + q * 4];
            acc1B[nb] = acc1A[nb];
            acc2B[nb] = acc2A[nb];
        }
        layer1_atom(wlds, lane, aiA0, aiA1, ajA0, ajA1, acc1A, acc2A);
        layer1_atom(wlds, lane, aiB0, aiB1, ajB0, ajB1, acc1B, acc2B);

        // ---- all atom frags dead: issue next pair's gathers + streams ----
        if (havenext) {
            const int neA = min(Pn * 32 + n,      n_edges - 1);
            const int neB = min(Pn * 32 + 16 + n, n_edges - 1);
            aiA0 = *(const s16x8*)&Af[(size_t)nbnA.x * 64 + q * 8];
            aiA1 = *(const s16x8*)&Af[(size_t)nbnA.x * 64 + 32 + q * 8];
            ajA0 = *(const s16x8*)&Af[(size_t)nbnA.y * 64 + q * 8];
            ajA1 = *(const s16x8*)&Af[(size_t)nbnA.y * 64 + 32 + q * 8];
            aiB0 = *(const s16x8*)&Af[(size_t)nbnB.x * 64 + q * 8];
            aiB1 = *(const s16x8*)&Af[(size_t)nbnB.x * 64 + 32 + q * 8];
            ajB0 = *(const s16x8*)&Af[(size_t)nbnB.y * 64 + q * 8];
            ajB1 = *(const s16x8*)&Af[(size_t)nbnB.y * 64 + 32 + q * 8];
            const float* nxrA = edge_ij + (size_t)neA * 64;
            const float* nxrB = edge_ij + (size_t)neB * 64;
            rxA0 = *(const float4*)(nxrA +      q * 4);
            rxA1 = *(const float4*)(nxrA + 16 + q * 4);
            rxA2 = *(const float4*)(nxrA + 32 + q * 4);
            rxA3 = *(const float4*)(nxrA + 48 + q * 4);
            rxB0 = *(const float4*)(nxrB +      q * 4);
            rxB1 = *(const float4*)(nxrB + 16 + q * 4);
            rxB2 = *(const float4*)(nxrB + 32 + q * 4);
            rxB3 = *(const float4*)(nxrB + 48 + q * 4);
            const float4 trbA = *(const float4*)(bonds_r + (size_t)neA * 16 + q * 4);
            const float4 trbB = *(const float4*)(bonds_r + (size_t)neB * 16 + q * 4);
            const int P2 = Pn + tstride;
            if (P2 < pairs) {
                nbnA = nb2[min(P2 * 32 + n,      n_edges - 1)];
                nbnB = nb2[min(P2 * 32 + 16 + n, n_edges - 1)];
            }
            // ---- layer-1 e_ij + finish, tiles A then B (loads in flight) --
            layer1_eij(wlds, lane, xfA0, xfA1, acc1A, acc2A);
            finish_tile(acc1A, acc2A, rbA, w3f, wrf, blds, out, E0, n_edges, q, n);
            layer1_eij(wlds, lane, xfB0, xfB1, acc1B, acc2B);
            finish_tile(acc1B, acc2B, rbB, w3f, wrf, blds, out, E0 + 16, n_edges, q, n);
            rbA = trbA; rbB = trbB;
            P = Pn;
            Pn = P + tstride;
            havenext = (Pn < pairs);
        } else {
            layer1_eij(wlds, lane, xfA0, xfA1, acc1A, acc2A);
            finish_tile(acc1A, acc2A, rbA, w3f, wrf, blds, out, E0, n_edges, q, n);
            layer1_eij(wlds, lane, xfB0, xfB1, acc1B, acc2B);
            finish_tile(acc1B, acc2B, rbB, w3f, wrf, blds, out, E0 + 16, n_edges, q, n);
            break;
        }
    }
}

// ---------------------------------------------------------------------------
extern "C" void kernel_launch(void* const* d_in, const int* in_sizes, int n_in,
                              void* d_out, int out_size, void* d_ws, size_t ws_size,
                              hipStream_t stream) {
    const float* atom_fea = (const float*)d_in[0];
    const float* edge_ij  = (const float*)d_in[1];
    const int*   nbr      = (const int*)  d_in[2];
    const float* bonds_r  = (const float*)d_in[3];
    const float* W1 = (const float*)d_in[4];
    const float* b1 = (const float*)d_in[5];
    const float* W2 = (const float*)d_in[6];
    const float* b2 = (const float*)d_in[7];
    const float* Wr = (const float*)d_in[8];
    const float* br = (const float*)d_in[9];
    const float* W3 = (const float*)d_in[10];
    const float* b3 = (const float*)d_in[11];
    float* out = (float*)d_out;
    unsigned short* Af = (unsigned short*)d_ws;   // 50000*64 bf16 = 6.4 MB

    const int n_atoms = in_sizes[0] / 64;
    const int n_edges = in_sizes[2] / 2;

    hipLaunchKernelGGL(atom_conv_kernel, dim3(2048), dim3(256), 0, stream,
                       atom_fea, Af, n_atoms * 64);

    hipLaunchKernelGGL(edge_kernel, dim3(1024), dim3(256), 0, stream,
                       Af, edge_ij, nbr, bonds_r,
                       W1, b1, W2, b2, W3, b3, Wr, br, out, n_edges);
}

// Round 19
// 252.457 us; speedup vs baseline: 1.1095x; 1.1095x over previous
//
#include <hip/hip_runtime.h>
#include <hip/hip_bf16.h>

typedef float    f32x4 __attribute__((ext_vector_type(4)));
typedef short    s16x8 __attribute__((ext_vector_type(8)));
typedef unsigned u32x4 __attribute__((ext_vector_type(4)));

__device__ __forceinline__ unsigned short f2bf(float f) {
    union { __hip_bfloat16 b; unsigned short u; } v;
    v.b = __float2bfloat16(f);
    return v.u;
}
// HW packed f32->bf16 (RTNE, same as __float2bfloat16): 2 converts / 1 op.
__device__ __forceinline__ unsigned cvtpk(float lo, float hi) {
    unsigned r;
    asm("v_cvt_pk_bf16_f32 %0, %1, %2" : "=v"(r) : "v"(lo), "v"(hi));
    return r;
}
__device__ __forceinline__ float sigf(float x)  {
    return __builtin_amdgcn_rcpf(1.0f + __expf(-x));
}

__device__ __forceinline__ s16x8 pack8(float4 a, float4 b) {
    union { u32x4 u; s16x8 v; } r;
    r.u[0] = cvtpk(a.x, a.y);
    r.u[1] = cvtpk(a.z, a.w);
    r.u[2] = cvtpk(b.x, b.y);
    r.u[3] = cvtpk(b.z, b.w);
    return r.v;
}

// ---------------------------------------------------------------------------
// Kernel 1: convert atom_fea fp32 -> bf16, rows PERMUTED into B-fragment
// split-half order: Af[a][(kh*4+q)*8 + jj] = bf16(atom[a][kh*32 + q*4 +
// (jj&3) + (jj>=4 ? 16 : 0)]).  Each lane's fragment = one 16 B load.
// ---------------------------------------------------------------------------
__global__ __launch_bounds__(256) void atom_conv_kernel(
    const float* __restrict__ atom_fea, unsigned short* __restrict__ Af, int total)
{
    int i = blockIdx.x * blockDim.x + threadIdx.x;
    const int stride = gridDim.x * blockDim.x;
    for (; i < total; i += stride) {
        int a = i >> 6, p = i & 63;
        int kh = p >> 5, q = (p >> 3) & 3, jj = p & 7;
        int k = kh * 32 + q * 4 + (jj & 3) + ((jj & 4) ? 16 : 0);
        Af[i] = f2bf(atom_fea[(size_t)a * 64 + k]);
    }
}

// ---------------------------------------------------------------------------
// Kernel 2: MFMA edge kernel. R19 = R17 (best, 254 us, VGPR 116) + two
// VGPR-neutral micro-levers:
//  1. merged-rcp h: silu(a1)*sig(a2) = a1*rcp((1+e^-a1)(1+e^-a2)) — 3 trans
//     ops vs 4 per element (trans = 1/4 VALU rate; 16 fewer trans/tile).
//     Overflow-safe: product inf -> rcp 0 = correct sigmoid limit.
//  2. s_setprio(1) around MFMA clusters (T5): persistent barrier-free waves
//     = diverse-phase regime where attn saw +4-7% (m191).
// Empirical envelope (R10-R18): VGPR must stay <=128 (>=176 halves waves);
// blocks/CU capped at 2 regardless of LDS. Spill check: WRITE == 400.0 MB.
// ---------------------------------------------------------------------------
#define NCH 40

__global__ __launch_bounds__(256, 1) void edge_kernel(
    const unsigned short* __restrict__ Af,
    const float* __restrict__ edge_ij,
    const int*   __restrict__ nbr,
    const float* __restrict__ bonds_r,
    const float* __restrict__ W1, const float* __restrict__ b1,
    const float* __restrict__ W2, const float* __restrict__ b2,
    const float* __restrict__ W3, const float* __restrict__ b3,
    const float* __restrict__ Wr, const float* __restrict__ br,
    float* __restrict__ out, int n_edges)
{
    __shared__ unsigned short wlds[NCH * 512];   // 40 KiB: W1 all + W2 atom
    __shared__ float blds[256];                  // b1 | b2 | b3 | br

    const int t    = threadIdx.x;
    const int wave = t >> 6;
    const int lane = t & 63;
    const int q    = lane >> 4;
    const int n    = lane & 15;

    // ---- stage W1 (24 chunks) + W2 atom-part (16 chunks) fragments ----
    for (int ch = 0; ch < NCH; ++ch) {
        int idx = t * 2;
        #pragma unroll
        for (int e2 = 0; e2 < 2; ++e2, ++idx) {
            const int l  = idx >> 3, j = idx & 7;
            const int lq = l >> 4, ln = l & 15;
            const int kk = (j < 4) ? (lq * 4 + j) : (16 + lq * 4 + (j - 4));
            float val;
            if (ch < 24) {                       // W1: kh 0..5, nb 0..3
                int kh = ch >> 2, nb = ch & 3;
                val = W1[(size_t)(kh * 32 + kk) * 64 + nb * 16 + ln];
            } else {                             // W2 atom part: kh 0..3
                int c2 = ch - 24; int kh = c2 >> 2, nb = c2 & 3;
                val = W2[(size_t)(kh * 32 + kk) * 64 + nb * 16 + ln];
            }
            wlds[ch * 512 + idx] = f2bf(val);
        }
    }
    if (t < 64)        blds[t] = b1[t];
    else if (t < 128)  blds[t] = b2[t - 64];
    else if (t < 192)  blds[t] = b3[t - 128];
    else               blds[t] = br[t - 192];

    // ---- W3 / Wr / W2-e_ij fragments persistent in registers ----
    s16x8 w3f[8], wrf[4], w2e[8];
    {
        const int ln = lane & 15;
        const int lq = lane >> 4;
        #pragma unroll
        for (int c2 = 0; c2 < 8; ++c2) {
            const int kh = c2 >> 2, nb = c2 & 3;
            s16x8 w, v;
            #pragma unroll
            for (int j = 0; j < 8; ++j) {
                const int kk = (j < 4) ? (lq * 4 + j) : (16 + lq * 4 + (j - 4));
                w[j] = (short)f2bf(W3[(size_t)(kh * 32 + kk) * 64 + nb * 16 + ln]);
                v[j] = (short)f2bf(W2[(size_t)((kh + 4) * 32 + kk) * 64 + nb * 16 + ln]);
            }
            w3f[c2] = w;
            w2e[c2] = v;
        }
        #pragma unroll
        for (int nb = 0; nb < 4; ++nb) {
            s16x8 w;
            #pragma unroll
            for (int j = 0; j < 8; ++j) {
                const int kk = (j < 4) ? (lq * 4 + j) : (16 + lq * 4 + (j - 4));
                w[j] = (short)(kk < 16 ? f2bf(Wr[(size_t)kk * 64 + nb * 16 + ln]) : 0);
            }
            wrf[nb] = w;
        }
    }
    __syncthreads();

    const int tiles   = (n_edges + 15) >> 4;
    const int tstride = gridDim.x * 4;
    int T = blockIdx.x * 4 + wave;
    if (T >= tiles) return;

    const int2* nb2 = (const int2*)nbr;

    // ---- prologue: current tile T loads + next tile indices ----
    int2 nbc = nb2[min(T * 16 + n, n_edges - 1)];
    int Tn = T + tstride;
    bool havenext = (Tn < tiles);
    int2 nbn = nbc;
    if (havenext) nbn = nb2[min(Tn * 16 + n, n_edges - 1)];

    const int e0 = min(T * 16 + n, n_edges - 1);
    s16x8 ai0 = *(const s16x8*)&Af[(size_t)nbc.x * 64 + q * 8];
    s16x8 ai1 = *(const s16x8*)&Af[(size_t)nbc.x * 64 + 32 + q * 8];
    s16x8 aj0 = *(const s16x8*)&Af[(size_t)nbc.y * 64 + q * 8];
    s16x8 aj1 = *(const s16x8*)&Af[(size_t)nbc.y * 64 + 32 + q * 8];
    const float* xr0 = edge_ij + (size_t)e0 * 64;
    float4 rx0 = *(const float4*)(xr0 +      q * 4);
    float4 rx1 = *(const float4*)(xr0 + 16 + q * 4);
    float4 rx2 = *(const float4*)(xr0 + 32 + q * 4);
    float4 rx3 = *(const float4*)(xr0 + 48 + q * 4);
    float4 rb  = *(const float4*)(bonds_r + (size_t)e0 * 16 + q * 4);

    while (true) {
        const int E0 = T * 16;

        // ---- pack current e_ij to bf16 B-frags (cvt_pk: 2 elems/op) ----
        s16x8 xf0 = pack8(rx0, rx1);
        s16x8 xf1 = pack8(rx2, rx3);

        // ---- acc init = biases (C layout row = ch = nb*16+q*4+j) ----
        f32x4 acc1[4], acc2[4];
        #pragma unroll
        for (int nb = 0; nb < 4; ++nb) {
            acc1[nb] = *(const f32x4*)&blds[nb * 16 + q * 4];
            acc2[nb] = *(const f32x4*)&blds[64 + nb * 16 + q * 4];
        }

        // ---- layer 1, atom part: kh 0..3 (consumes ai0..aj1) ----
        __builtin_amdgcn_s_setprio(1);
        #pragma unroll
        for (int nb = 0; nb < 4; ++nb) {
            s16x8 w;
            w = *(const s16x8*)&wlds[( 0 + nb) * 512 + lane * 8];
            acc1[nb] = __builtin_amdgcn_mfma_f32_16x16x32_bf16(w, ai0, acc1[nb], 0, 0, 0);
            w = *(const s16x8*)&wlds[( 4 + nb) * 512 + lane * 8];
            acc1[nb] = __builtin_amdgcn_mfma_f32_16x16x32_bf16(w, ai1, acc1[nb], 0, 0, 0);
            w = *(const s16x8*)&wlds[( 8 + nb) * 512 + lane * 8];
            acc1[nb] = __builtin_amdgcn_mfma_f32_16x16x32_bf16(w, aj0, acc1[nb], 0, 0, 0);
            w = *(const s16x8*)&wlds[(12 + nb) * 512 + lane * 8];
            acc1[nb] = __builtin_amdgcn_mfma_f32_16x16x32_bf16(w, aj1, acc1[nb], 0, 0, 0);
            w = *(const s16x8*)&wlds[(24 + nb) * 512 + lane * 8];
            acc2[nb] = __builtin_amdgcn_mfma_f32_16x16x32_bf16(w, ai0, acc2[nb], 0, 0, 0);
            w = *(const s16x8*)&wlds[(28 + nb) * 512 + lane * 8];
            acc2[nb] = __builtin_amdgcn_mfma_f32_16x16x32_bf16(w, ai1, acc2[nb], 0, 0, 0);
            w = *(const s16x8*)&wlds[(32 + nb) * 512 + lane * 8];
            acc2[nb] = __builtin_amdgcn_mfma_f32_16x16x32_bf16(w, aj0, acc2[nb], 0, 0, 0);
            w = *(const s16x8*)&wlds[(36 + nb) * 512 + lane * 8];
            acc2[nb] = __builtin_amdgcn_mfma_f32_16x16x32_bf16(w, aj1, acc2[nb], 0, 0, 0);
        }
        __builtin_amdgcn_s_setprio(0);

        // ---- atom frags dead: issue NEXT tile's gathers + stream loads ----
        s16x8 nai0 = ai0, nai1 = ai1, naj0 = aj0, naj1 = aj1;
        float4 nrx0 = rx0, nrx1 = rx1, nrx2 = rx2, nrx3 = rx3, nrb = rb;
        if (havenext) {
            const int ne = min(Tn * 16 + n, n_edges - 1);
            nai0 = *(const s16x8*)&Af[(size_t)nbn.x * 64 + q * 8];
            nai1 = *(const s16x8*)&Af[(size_t)nbn.x * 64 + 32 + q * 8];
            naj0 = *(const s16x8*)&Af[(size_t)nbn.y * 64 + q * 8];
            naj1 = *(const s16x8*)&Af[(size_t)nbn.y * 64 + 32 + q * 8];
            const float* nxr = edge_ij + (size_t)ne * 64;
            nrx0 = *(const float4*)(nxr +      q * 4);
            nrx1 = *(const float4*)(nxr + 16 + q * 4);
            nrx2 = *(const float4*)(nxr + 32 + q * 4);
            nrx3 = *(const float4*)(nxr + 48 + q * 4);
            nrb  = *(const float4*)(bonds_r + (size_t)ne * 16 + q * 4);
            const int T2 = Tn + tstride;
            if (T2 < tiles) nbn = nb2[min(T2 * 16 + n, n_edges - 1)];
        }

        // ---- layer 1, e_ij part: kh 4..5 (W1 from LDS, W2 from regs) ----
        __builtin_amdgcn_s_setprio(1);
        #pragma unroll
        for (int nb = 0; nb < 4; ++nb) {
            s16x8 w;
            w = *(const s16x8*)&wlds[(16 + nb) * 512 + lane * 8];
            acc1[nb] = __builtin_amdgcn_mfma_f32_16x16x32_bf16(w, xf0, acc1[nb], 0, 0, 0);
            w = *(const s16x8*)&wlds[(20 + nb) * 512 + lane * 8];
            acc1[nb] = __builtin_amdgcn_mfma_f32_16x16x32_bf16(w, xf1, acc1[nb], 0, 0, 0);
            acc2[nb] = __builtin_amdgcn_mfma_f32_16x16x32_bf16(w2e[nb],     xf0, acc2[nb], 0, 0, 0);
            acc2[nb] = __builtin_amdgcn_mfma_f32_16x16x32_bf16(w2e[4 + nb], xf1, acc2[nb], 0, 0, 0);
        }
        __builtin_amdgcn_s_setprio(0);

        // ---- gate input from current bonds ----
        s16x8 bfrag;
        {
            union { u32x4 u; s16x8 v; } B;
            B.u[0] = cvtpk(rb.x, rb.y);
            B.u[1] = cvtpk(rb.z, rb.w);
            B.u[2] = 0; B.u[3] = 0;
            bfrag = B.v;
        }

        // ---- h lane-local, merged rcp: a1*rcp((1+e^-a1)(1+e^-a2)) ----
        f32x4 h[4];
        #pragma unroll
        for (int nb = 0; nb < 4; ++nb) {
            f32x4 s1 = acc1[nb], s2 = acc2[nb], hv;
            #pragma unroll
            for (int j = 0; j < 4; ++j) {
                float ea = __expf(-s1[j]);
                float eb = __expf(-s2[j]);
                hv[j] = s1[j] * __builtin_amdgcn_rcpf((1.0f + ea) * (1.0f + eb));
            }
            h[nb] = hv;
        }
        s16x8 hf0, hf1;
        {
            union { u32x4 u; s16x8 v; } H0, H1;
            H0.u[0] = cvtpk(h[0][0], h[0][1]);
            H0.u[1] = cvtpk(h[0][2], h[0][3]);
            H0.u[2] = cvtpk(h[1][0], h[1][1]);
            H0.u[3] = cvtpk(h[1][2], h[1][3]);
            H1.u[0] = cvtpk(h[2][0], h[2][1]);
            H1.u[1] = cvtpk(h[2][2], h[2][3]);
            H1.u[2] = cvtpk(h[3][0], h[3][1]);
            H1.u[3] = cvtpk(h[3][2], h[3][3]);
            hf0 = H0.v; hf1 = H1.v;
        }

        // ---- layer 2 (h @ W3) and gate (bonds @ Wr): register weights ----
        f32x4 a3[4], g[4];
        #pragma unroll
        for (int nb = 0; nb < 4; ++nb) { a3[nb] = (f32x4){0,0,0,0}; g[nb] = (f32x4){0,0,0,0}; }
        __builtin_amdgcn_s_setprio(1);
        #pragma unroll
        for (int nb = 0; nb < 4; ++nb) {
            a3[nb] = __builtin_amdgcn_mfma_f32_16x16x32_bf16(hf0, w3f[nb],     a3[nb], 0, 0, 0);
            a3[nb] = __builtin_amdgcn_mfma_f32_16x16x32_bf16(hf1, w3f[4 + nb], a3[nb], 0, 0, 0);
            g[nb]  = __builtin_amdgcn_mfma_f32_16x16x32_bf16(bfrag, wrf[nb],   g[nb],  0, 0, 0);
        }
        __builtin_amdgcn_s_setprio(0);

        // ---- out[edge q*4+j][oc nb*16+n] = silu(a3+b3)*(g+br) ----
        float* outp = out + (size_t)(E0 + q * 4) * 64 + n;
        if (E0 + 16 <= n_edges) {
            #pragma unroll
            for (int nb = 0; nb < 4; ++nb) {
                const float b3s = blds[128 + nb * 16 + n];
                const float brs = blds[192 + nb * 16 + n];
                f32x4 s  = a3[nb] + b3s;
                f32x4 gg = g[nb] + brs;
                f32x4 o;
                #pragma unroll
                for (int j = 0; j < 4; ++j)
                    o[j] = s[j] * sigf(s[j]) * gg[j];
                #pragma unroll
                for (int j = 0; j < 4; ++j)
                    outp[j * 64 + nb * 16] = o[j];
            }
        } else {
            #pragma unroll
            for (int nb = 0; nb < 4; ++nb) {
                const float b3s = blds[128 + nb * 16 + n];
                const float brs = blds[192 + nb * 16 + n];
                f32x4 s  = a3[nb] + b3s;
                f32x4 gg = g[nb] + brs;
                #pragma unroll
                for (int j = 0; j < 4; ++j)
                    if (E0 + q * 4 + j < n_edges)
                        outp[j * 64 + nb * 16] = s[j] * sigf(s[j]) * gg[j];
            }
        }

        if (!havenext) break;
        // ---- advance: next becomes current ----
        T = Tn;
        Tn = T + tstride;
        havenext = (Tn < tiles);
        ai0 = nai0; ai1 = nai1; aj0 = naj0; aj1 = naj1;
        rx0 = nrx0; rx1 = nrx1; rx2 = nrx2; rx3 = nrx3; rb = nrb;
    }
}

// ---------------------------------------------------------------------------
extern "C" void kernel_launch(void* const* d_in, const int* in_sizes, int n_in,
                              void* d_out, int out_size, void* d_ws, size_t ws_size,
                              hipStream_t stream) {
    const float* atom_fea = (const float*)d_in[0];
    const float* edge_ij  = (const float*)d_in[1];
    const int*   nbr      = (const int*)  d_in[2];
    const float* bonds_r  = (const float*)d_in[3];
    const float* W1 = (const float*)d_in[4];
    const float* b1 = (const float*)d_in[5];
    const float* W2 = (const float*)d_in[6];
    const float* b2 = (const float*)d_in[7];
    const float* Wr = (const float*)d_in[8];
    const float* br = (const float*)d_in[9];
    const float* W3 = (const float*)d_in[10];
    const float* b3 = (const float*)d_in[11];
    float* out = (float*)d_out;
    unsigned short* Af = (unsigned short*)d_ws;   // 50000*64 bf16 = 6.4 MB

    const int n_atoms = in_sizes[0] / 64;
    const int n_edges = in_sizes[2] / 2;

    hipLaunchKernelGGL(atom_conv_kernel, dim3(2048), dim3(256), 0, stream,
                       atom_fea, Af, n_atoms * 64);

    hipLaunchKernelGGL(edge_kernel, dim3(1536), dim3(256), 0, stream,
                       Af, edge_ij, nbr, bonds_r,
                       W1, b1, W2, b2, W3, b3, Wr, br, out, n_edges);
}

// Round 20
// 246.508 us; speedup vs baseline: 1.1363x; 1.0241x over previous
//
#include <hip/hip_runtime.h>
#include <hip/hip_bf16.h>

typedef float    f32x4 __attribute__((ext_vector_type(4)));
typedef short    s16x8 __attribute__((ext_vector_type(8)));
typedef unsigned u32x4 __attribute__((ext_vector_type(4)));

__device__ __forceinline__ unsigned short f2bf(float f) {
    union { __hip_bfloat16 b; unsigned short u; } v;
    v.b = __float2bfloat16(f);
    return v.u;
}
// HW packed f32->bf16 (RTNE, same as __float2bfloat16): 2 converts / 1 op.
__device__ __forceinline__ unsigned cvtpk(float lo, float hi) {
    unsigned r;
    asm("v_cvt_pk_bf16_f32 %0, %1, %2" : "=v"(r) : "v"(lo), "v"(hi));
    return r;
}
__device__ __forceinline__ float sigf(float x)  {
    return __builtin_amdgcn_rcpf(1.0f + __expf(-x));
}

__device__ __forceinline__ s16x8 pack8(float4 a, float4 b) {
    union { u32x4 u; s16x8 v; } r;
    r.u[0] = cvtpk(a.x, a.y);
    r.u[1] = cvtpk(a.z, a.w);
    r.u[2] = cvtpk(b.x, b.y);
    r.u[3] = cvtpk(b.z, b.w);
    return r.v;
}

// ---------------------------------------------------------------------------
// Kernel 1: convert atom_fea fp32 -> bf16, rows PERMUTED into B-fragment
// split-half order: Af[a][(kh*4+q)*8 + jj] = bf16(atom[a][kh*32 + q*4 +
// (jj&3) + (jj>=4 ? 16 : 0)]).  Each lane's fragment = one 16 B load.
// ---------------------------------------------------------------------------
__global__ __launch_bounds__(256) void atom_conv_kernel(
    const float* __restrict__ atom_fea, unsigned short* __restrict__ Af, int total)
{
    int i = blockIdx.x * blockDim.x + threadIdx.x;
    const int stride = gridDim.x * blockDim.x;
    for (; i < total; i += stride) {
        int a = i >> 6, p = i & 63;
        int kh = p >> 5, q = (p >> 3) & 3, jj = p & 7;
        int k = kh * 32 + q * 4 + (jj & 3) + ((jj & 4) ? 16 : 0);
        Af[i] = f2bf(atom_fea[(size_t)a * 64 + k]);
    }
}

// ---------------------------------------------------------------------------
// Kernel 2: MFMA edge kernel. R20 = R19 body (best config: NCH=40, w2e/w3f/
// wrf register weights, merged-rcp h, setprio) at 512-thread/8-wave blocks:
// 2 blocks/CU (LDS-granularity-capped, immovable per R13-R17) x 8 waves =
// 16 waves/CU — 2x the 256-thread TLP. bounds (512,2): the PROVEN 512-thr
// bounds (R4/R5/R8 all correct; the single NaN was (512,1), now avoided).
// Cap 128 >= demand 116 -> no clamp-spill. Staging runs on t<256 only,
// byte-identical to R17/R19's proven loop. Grid 512 = exactly 2 blocks/CU,
// one balanced batch. Spill check: WRITE == 400.0 MB.
// ---------------------------------------------------------------------------
#define NCH 40

__global__ __launch_bounds__(512, 2) void edge_kernel(
    const unsigned short* __restrict__ Af,
    const float* __restrict__ edge_ij,
    const int*   __restrict__ nbr,
    const float* __restrict__ bonds_r,
    const float* __restrict__ W1, const float* __restrict__ b1,
    const float* __restrict__ W2, const float* __restrict__ b2,
    const float* __restrict__ W3, const float* __restrict__ b3,
    const float* __restrict__ Wr, const float* __restrict__ br,
    float* __restrict__ out, int n_edges)
{
    __shared__ unsigned short wlds[NCH * 512];   // 40 KiB: W1 all + W2 atom
    __shared__ float blds[256];                  // b1 | b2 | b3 | br

    const int t    = threadIdx.x;
    const int wave = t >> 6;
    const int lane = t & 63;
    const int q    = lane >> 4;
    const int n    = lane & 15;

    // ---- stage W1 (24 chunks) + W2 atom-part (16 chunks): t<256 only,
    //      byte-identical to the proven R17/R19 staging loop ----
    if (t < 256) {
        for (int ch = 0; ch < NCH; ++ch) {
            int idx = t * 2;
            #pragma unroll
            for (int e2 = 0; e2 < 2; ++e2, ++idx) {
                const int l  = idx >> 3, j = idx & 7;
                const int lq = l >> 4, ln = l & 15;
                const int kk = (j < 4) ? (lq * 4 + j) : (16 + lq * 4 + (j - 4));
                float val;
                if (ch < 24) {                       // W1: kh 0..5, nb 0..3
                    int kh = ch >> 2, nb = ch & 3;
                    val = W1[(size_t)(kh * 32 + kk) * 64 + nb * 16 + ln];
                } else {                             // W2 atom part: kh 0..3
                    int c2 = ch - 24; int kh = c2 >> 2, nb = c2 & 3;
                    val = W2[(size_t)(kh * 32 + kk) * 64 + nb * 16 + ln];
                }
                wlds[ch * 512 + idx] = f2bf(val);
            }
        }
        if (t < 64)        blds[t] = b1[t];
        else if (t < 128)  blds[t] = b2[t - 64];
        else if (t < 192)  blds[t] = b3[t - 128];
        else               blds[t] = br[t - 192];
    }

    // ---- W3 / Wr / W2-e_ij fragments persistent in registers ----
    s16x8 w3f[8], wrf[4], w2e[8];
    {
        const int ln = lane & 15;
        const int lq = lane >> 4;
        #pragma unroll
        for (int c2 = 0; c2 < 8; ++c2) {
            const int kh = c2 >> 2, nb = c2 & 3;
            s16x8 w, v;
            #pragma unroll
            for (int j = 0; j < 8; ++j) {
                const int kk = (j < 4) ? (lq * 4 + j) : (16 + lq * 4 + (j - 4));
                w[j] = (short)f2bf(W3[(size_t)(kh * 32 + kk) * 64 + nb * 16 + ln]);
                v[j] = (short)f2bf(W2[(size_t)((kh + 4) * 32 + kk) * 64 + nb * 16 + ln]);
            }
            w3f[c2] = w;
            w2e[c2] = v;
        }
        #pragma unroll
        for (int nb = 0; nb < 4; ++nb) {
            s16x8 w;
            #pragma unroll
            for (int j = 0; j < 8; ++j) {
                const int kk = (j < 4) ? (lq * 4 + j) : (16 + lq * 4 + (j - 4));
                w[j] = (short)(kk < 16 ? f2bf(Wr[(size_t)kk * 64 + nb * 16 + ln]) : 0);
            }
            wrf[nb] = w;
        }
    }
    __syncthreads();

    const int tiles   = (n_edges + 15) >> 4;
    const int tstride = gridDim.x * 8;
    int T = blockIdx.x * 8 + wave;
    if (T >= tiles) return;

    const int2* nb2 = (const int2*)nbr;

    // ---- prologue: current tile T loads + next tile indices ----
    int2 nbc = nb2[min(T * 16 + n, n_edges - 1)];
    int Tn = T + tstride;
    bool havenext = (Tn < tiles);
    int2 nbn = nbc;
    if (havenext) nbn = nb2[min(Tn * 16 + n, n_edges - 1)];

    const int e0 = min(T * 16 + n, n_edges - 1);
    s16x8 ai0 = *(const s16x8*)&Af[(size_t)nbc.x * 64 + q * 8];
    s16x8 ai1 = *(const s16x8*)&Af[(size_t)nbc.x * 64 + 32 + q * 8];
    s16x8 aj0 = *(const s16x8*)&Af[(size_t)nbc.y * 64 + q * 8];
    s16x8 aj1 = *(const s16x8*)&Af[(size_t)nbc.y * 64 + 32 + q * 8];
    const float* xr0 = edge_ij + (size_t)e0 * 64;
    float4 rx0 = *(const float4*)(xr0 +      q * 4);
    float4 rx1 = *(const float4*)(xr0 + 16 + q * 4);
    float4 rx2 = *(const float4*)(xr0 + 32 + q * 4);
    float4 rx3 = *(const float4*)(xr0 + 48 + q * 4);
    float4 rb  = *(const float4*)(bonds_r + (size_t)e0 * 16 + q * 4);

    while (true) {
        const int E0 = T * 16;

        // ---- pack current e_ij to bf16 B-frags (cvt_pk: 2 elems/op) ----
        s16x8 xf0 = pack8(rx0, rx1);
        s16x8 xf1 = pack8(rx2, rx3);

        // ---- acc init = biases (C layout row = ch = nb*16+q*4+j) ----
        f32x4 acc1[4], acc2[4];
        #pragma unroll
        for (int nb = 0; nb < 4; ++nb) {
            acc1[nb] = *(const f32x4*)&blds[nb * 16 + q * 4];
            acc2[nb] = *(const f32x4*)&blds[64 + nb * 16 + q * 4];
        }

        // ---- layer 1, atom part: kh 0..3 (consumes ai0..aj1) ----
        __builtin_amdgcn_s_setprio(1);
        #pragma unroll
        for (int nb = 0; nb < 4; ++nb) {
            s16x8 w;
            w = *(const s16x8*)&wlds[( 0 + nb) * 512 + lane * 8];
            acc1[nb] = __builtin_amdgcn_mfma_f32_16x16x32_bf16(w, ai0, acc1[nb], 0, 0, 0);
            w = *(const s16x8*)&wlds[( 4 + nb) * 512 + lane * 8];
            acc1[nb] = __builtin_amdgcn_mfma_f32_16x16x32_bf16(w, ai1, acc1[nb], 0, 0, 0);
            w = *(const s16x8*)&wlds[( 8 + nb) * 512 + lane * 8];
            acc1[nb] = __builtin_amdgcn_mfma_f32_16x16x32_bf16(w, aj0, acc1[nb], 0, 0, 0);
            w = *(const s16x8*)&wlds[(12 + nb) * 512 + lane * 8];
            acc1[nb] = __builtin_amdgcn_mfma_f32_16x16x32_bf16(w, aj1, acc1[nb], 0, 0, 0);
            w = *(const s16x8*)&wlds[(24 + nb) * 512 + lane * 8];
            acc2[nb] = __builtin_amdgcn_mfma_f32_16x16x32_bf16(w, ai0, acc2[nb], 0, 0, 0);
            w = *(const s16x8*)&wlds[(28 + nb) * 512 + lane * 8];
            acc2[nb] = __builtin_amdgcn_mfma_f32_16x16x32_bf16(w, ai1, acc2[nb], 0, 0, 0);
            w = *(const s16x8*)&wlds[(32 + nb) * 512 + lane * 8];
            acc2[nb] = __builtin_amdgcn_mfma_f32_16x16x32_bf16(w, aj0, acc2[nb], 0, 0, 0);
            w = *(const s16x8*)&wlds[(36 + nb) * 512 + lane * 8];
            acc2[nb] = __builtin_amdgcn_mfma_f32_16x16x32_bf16(w, aj1, acc2[nb], 0, 0, 0);
        }
        __builtin_amdgcn_s_setprio(0);

        // ---- atom frags dead: issue NEXT tile's gathers + stream loads ----
        s16x8 nai0 = ai0, nai1 = ai1, naj0 = aj0, naj1 = aj1;
        float4 nrx0 = rx0, nrx1 = rx1, nrx2 = rx2, nrx3 = rx3, nrb = rb;
        if (havenext) {
            const int ne = min(Tn * 16 + n, n_edges - 1);
            nai0 = *(const s16x8*)&Af[(size_t)nbn.x * 64 + q * 8];
            nai1 = *(const s16x8*)&Af[(size_t)nbn.x * 64 + 32 + q * 8];
            naj0 = *(const s16x8*)&Af[(size_t)nbn.y * 64 + q * 8];
            naj1 = *(const s16x8*)&Af[(size_t)nbn.y * 64 + 32 + q * 8];
            const float* nxr = edge_ij + (size_t)ne * 64;
            nrx0 = *(const float4*)(nxr +      q * 4);
            nrx1 = *(const float4*)(nxr + 16 + q * 4);
            nrx2 = *(const float4*)(nxr + 32 + q * 4);
            nrx3 = *(const float4*)(nxr + 48 + q * 4);
            nrb  = *(const float4*)(bonds_r + (size_t)ne * 16 + q * 4);
            const int T2 = Tn + tstride;
            if (T2 < tiles) nbn = nb2[min(T2 * 16 + n, n_edges - 1)];
        }

        // ---- layer 1, e_ij part: kh 4..5 (W1 from LDS, W2 from regs) ----
        __builtin_amdgcn_s_setprio(1);
        #pragma unroll
        for (int nb = 0; nb < 4; ++nb) {
            s16x8 w;
            w = *(const s16x8*)&wlds[(16 + nb) * 512 + lane * 8];
            acc1[nb] = __builtin_amdgcn_mfma_f32_16x16x32_bf16(w, xf0, acc1[nb], 0, 0, 0);
            w = *(const s16x8*)&wlds[(20 + nb) * 512 + lane * 8];
            acc1[nb] = __builtin_amdgcn_mfma_f32_16x16x32_bf16(w, xf1, acc1[nb], 0, 0, 0);
            acc2[nb] = __builtin_amdgcn_mfma_f32_16x16x32_bf16(w2e[nb],     xf0, acc2[nb], 0, 0, 0);
            acc2[nb] = __builtin_amdgcn_mfma_f32_16x16x32_bf16(w2e[4 + nb], xf1, acc2[nb], 0, 0, 0);
        }
        __builtin_amdgcn_s_setprio(0);

        // ---- gate input from current bonds ----
        s16x8 bfrag;
        {
            union { u32x4 u; s16x8 v; } B;
            B.u[0] = cvtpk(rb.x, rb.y);
            B.u[1] = cvtpk(rb.z, rb.w);
            B.u[2] = 0; B.u[3] = 0;
            bfrag = B.v;
        }

        // ---- h lane-local, merged rcp: a1*rcp((1+e^-a1)(1+e^-a2)) ----
        f32x4 h[4];
        #pragma unroll
        for (int nb = 0; nb < 4; ++nb) {
            f32x4 s1 = acc1[nb], s2 = acc2[nb], hv;
            #pragma unroll
            for (int j = 0; j < 4; ++j) {
                float ea = __expf(-s1[j]);
                float eb = __expf(-s2[j]);
                hv[j] = s1[j] * __builtin_amdgcn_rcpf((1.0f + ea) * (1.0f + eb));
            }
            h[nb] = hv;
        }
        s16x8 hf0, hf1;
        {
            union { u32x4 u; s16x8 v; } H0, H1;
            H0.u[0] = cvtpk(h[0][0], h[0][1]);
            H0.u[1] = cvtpk(h[0][2], h[0][3]);
            H0.u[2] = cvtpk(h[1][0], h[1][1]);
            H0.u[3] = cvtpk(h[1][2], h[1][3]);
            H1.u[0] = cvtpk(h[2][0], h[2][1]);
            H1.u[1] = cvtpk(h[2][2], h[2][3]);
            H1.u[2] = cvtpk(h[3][0], h[3][1]);
            H1.u[3] = cvtpk(h[3][2], h[3][3]);
            hf0 = H0.v; hf1 = H1.v;
        }

        // ---- layer 2 (h @ W3) and gate (bonds @ Wr): register weights ----
        f32x4 a3[4], g[4];
        #pragma unroll
        for (int nb = 0; nb < 4; ++nb) { a3[nb] = (f32x4){0,0,0,0}; g[nb] = (f32x4){0,0,0,0}; }
        __builtin_amdgcn_s_setprio(1);
        #pragma unroll
        for (int nb = 0; nb < 4; ++nb) {
            a3[nb] = __builtin_amdgcn_mfma_f32_16x16x32_bf16(hf0, w3f[nb],     a3[nb], 0, 0, 0);
            a3[nb] = __builtin_amdgcn_mfma_f32_16x16x32_bf16(hf1, w3f[4 + nb], a3[nb], 0, 0, 0);
            g[nb]  = __builtin_amdgcn_mfma_f32_16x16x32_bf16(bfrag, wrf[nb],   g[nb],  0, 0, 0);
        }
        __builtin_amdgcn_s_setprio(0);

        // ---- out[edge q*4+j][oc nb*16+n] = silu(a3+b3)*(g+br) ----
        float* outp = out + (size_t)(E0 + q * 4) * 64 + n;
        if (E0 + 16 <= n_edges) {
            #pragma unroll
            for (int nb = 0; nb < 4; ++nb) {
                const float b3s = blds[128 + nb * 16 + n];
                const float brs = blds[192 + nb * 16 + n];
                f32x4 s  = a3[nb] + b3s;
                f32x4 gg = g[nb] + brs;
                f32x4 o;
                #pragma unroll
                for (int j = 0; j < 4; ++j)
                    o[j] = s[j] * sigf(s[j]) * gg[j];
                #pragma unroll
                for (int j = 0; j < 4; ++j)
                    outp[j * 64 + nb * 16] = o[j];
            }
        } else {
            #pragma unroll
            for (int nb = 0; nb < 4; ++nb) {
                const float b3s = blds[128 + nb * 16 + n];
                const float brs = blds[192 + nb * 16 + n];
                f32x4 s  = a3[nb] + b3s;
                f32x4 gg = g[nb] + brs;
                #pragma unroll
                for (int j = 0; j < 4; ++j)
                    if (E0 + q * 4 + j < n_edges)
                        outp[j * 64 + nb * 16] = s[j] * sigf(s[j]) * gg[j];
            }
        }

        if (!havenext) break;
        // ---- advance: next becomes current ----
        T = Tn;
        Tn = T + tstride;
        havenext = (Tn < tiles);
        ai0 = nai0; ai1 = nai1; aj0 = naj0; aj1 = naj1;
        rx0 = nrx0; rx1 = nrx1; rx2 = nrx2; rx3 = nrx3; rb = nrb;
    }
}

// ---------------------------------------------------------------------------
extern "C" void kernel_launch(void* const* d_in, const int* in_sizes, int n_in,
                              void* d_out, int out_size, void* d_ws, size_t ws_size,
                              hipStream_t stream) {
    const float* atom_fea = (const float*)d_in[0];
    const float* edge_ij  = (const float*)d_in[1];
    const int*   nbr      = (const int*)  d_in[2];
    const float* bonds_r  = (const float*)d_in[3];
    const float* W1 = (const float*)d_in[4];
    const float* b1 = (const float*)d_in[5];
    const float* W2 = (const float*)d_in[6];
    const float* b2 = (const float*)d_in[7];
    const float* Wr = (const float*)d_in[8];
    const float* br = (const float*)d_in[9];
    const float* W3 = (const float*)d_in[10];
    const float* b3 = (const float*)d_in[11];
    float* out = (float*)d_out;
    unsigned short* Af = (unsigned short*)d_ws;   // 50000*64 bf16 = 6.4 MB

    const int n_atoms = in_sizes[0] / 64;
    const int n_edges = in_sizes[2] / 2;

    hipLaunchKernelGGL(atom_conv_kernel, dim3(2048), dim3(256), 0, stream,
                       atom_fea, Af, n_atoms * 64);

    hipLaunchKernelGGL(edge_kernel, dim3(512), dim3(512), 0, stream,
                       Af, edge_ij, nbr, bonds_r,
                       W1, b1, W2, b2, W3, b3, Wr, br, out, n_edges);
}

// Round 21
// 243.820 us; speedup vs baseline: 1.1488x; 1.0110x over previous
//
#include <hip/hip_runtime.h>
#include <hip/hip_bf16.h>

typedef float    f32x4 __attribute__((ext_vector_type(4)));
typedef short    s16x8 __attribute__((ext_vector_type(8)));
typedef unsigned u32x4 __attribute__((ext_vector_type(4)));

__device__ __forceinline__ unsigned short f2bf(float f) {
    union { __hip_bfloat16 b; unsigned short u; } v;
    v.b = __float2bfloat16(f);
    return v.u;
}
// HW packed f32->bf16 (RTNE, same as __float2bfloat16): 2 converts / 1 op.
__device__ __forceinline__ unsigned cvtpk(float lo, float hi) {
    unsigned r;
    asm("v_cvt_pk_bf16_f32 %0, %1, %2" : "=v"(r) : "v"(lo), "v"(hi));
    return r;
}
__device__ __forceinline__ float sigf(float x)  {
    return __builtin_amdgcn_rcpf(1.0f + __expf(-x));
}

__device__ __forceinline__ s16x8 pack8(float4 a, float4 b) {
    union { u32x4 u; s16x8 v; } r;
    r.u[0] = cvtpk(a.x, a.y);
    r.u[1] = cvtpk(a.z, a.w);
    r.u[2] = cvtpk(b.x, b.y);
    r.u[3] = cvtpk(b.z, b.w);
    return r.v;
}

// ---------------------------------------------------------------------------
// Kernel 1: convert atom_fea fp32 -> bf16, rows PERMUTED into B-fragment
// split-half order: Af[a][(kh*4+q)*8 + jj] = bf16(atom[a][kh*32 + q*4 +
// (jj&3) + (jj>=4 ? 16 : 0)]).  Each lane's fragment = one 16 B load.
// ---------------------------------------------------------------------------
__global__ __launch_bounds__(256) void atom_conv_kernel(
    const float* __restrict__ atom_fea, unsigned short* __restrict__ Af, int total)
{
    int i = blockIdx.x * blockDim.x + threadIdx.x;
    const int stride = gridDim.x * blockDim.x;
    for (; i < total; i += stride) {
        int a = i >> 6, p = i & 63;
        int kh = p >> 5, q = (p >> 3) & 3, jj = p & 7;
        int k = kh * 32 + q * 4 + (jj & 3) + ((jj & 4) ? 16 : 0);
        Af[i] = f2bf(atom_fea[(size_t)a * 64 + k]);
    }
}

// ---------------------------------------------------------------------------
// Kernel 2: R21 = R20 (512thr/(512,2), NCH=40, reg weights, merged-rcp,
// setprio) + DEPTH-2 STREAM PREFETCH. Cycle audit: ~600 cyc work/tile vs
// ~6000 cyc/tile/SIMD observed -> waves stall ~90%; stream loads (HBM ~900
// cyc, m126) were issued only ~600-800 cyc before their top-of-loop use.
// Streams need no index chain, so tile T+2's edge_ij/bonds load into a 2nd
// reg set (+~24 VGPR -> ~122 <= 128 cap), rotated via reg-copy where the
// current set dies. bfrag pack moved to loop top (kills cb early). Gathers
// (L2/L3, covered) stay depth-1. Spill gate: WRITE == 400.0 MB.
// ---------------------------------------------------------------------------
#define NCH 40

__global__ __launch_bounds__(512, 2) void edge_kernel(
    const unsigned short* __restrict__ Af,
    const float* __restrict__ edge_ij,
    const int*   __restrict__ nbr,
    const float* __restrict__ bonds_r,
    const float* __restrict__ W1, const float* __restrict__ b1,
    const float* __restrict__ W2, const float* __restrict__ b2,
    const float* __restrict__ W3, const float* __restrict__ b3,
    const float* __restrict__ Wr, const float* __restrict__ br,
    float* __restrict__ out, int n_edges)
{
    __shared__ unsigned short wlds[NCH * 512];   // 40 KiB: W1 all + W2 atom
    __shared__ float blds[256];                  // b1 | b2 | b3 | br

    const int t    = threadIdx.x;
    const int wave = t >> 6;
    const int lane = t & 63;
    const int q    = lane >> 4;
    const int n    = lane & 15;

    // ---- stage W1 (24 chunks) + W2 atom-part (16 chunks): t<256 only ----
    if (t < 256) {
        for (int ch = 0; ch < NCH; ++ch) {
            int idx = t * 2;
            #pragma unroll
            for (int e2 = 0; e2 < 2; ++e2, ++idx) {
                const int l  = idx >> 3, j = idx & 7;
                const int lq = l >> 4, ln = l & 15;
                const int kk = (j < 4) ? (lq * 4 + j) : (16 + lq * 4 + (j - 4));
                float val;
                if (ch < 24) {                       // W1: kh 0..5, nb 0..3
                    int kh = ch >> 2, nb = ch & 3;
                    val = W1[(size_t)(kh * 32 + kk) * 64 + nb * 16 + ln];
                } else {                             // W2 atom part: kh 0..3
                    int c2 = ch - 24; int kh = c2 >> 2, nb = c2 & 3;
                    val = W2[(size_t)(kh * 32 + kk) * 64 + nb * 16 + ln];
                }
                wlds[ch * 512 + idx] = f2bf(val);
            }
        }
        if (t < 64)        blds[t] = b1[t];
        else if (t < 128)  blds[t] = b2[t - 64];
        else if (t < 192)  blds[t] = b3[t - 128];
        else               blds[t] = br[t - 192];
    }

    // ---- W3 / Wr / W2-e_ij fragments persistent in registers ----
    s16x8 w3f[8], wrf[4], w2e[8];
    {
        const int ln = lane & 15;
        const int lq = lane >> 4;
        #pragma unroll
        for (int c2 = 0; c2 < 8; ++c2) {
            const int kh = c2 >> 2, nb = c2 & 3;
            s16x8 w, v;
            #pragma unroll
            for (int j = 0; j < 8; ++j) {
                const int kk = (j < 4) ? (lq * 4 + j) : (16 + lq * 4 + (j - 4));
                w[j] = (short)f2bf(W3[(size_t)(kh * 32 + kk) * 64 + nb * 16 + ln]);
                v[j] = (short)f2bf(W2[(size_t)((kh + 4) * 32 + kk) * 64 + nb * 16 + ln]);
            }
            w3f[c2] = w;
            w2e[c2] = v;
        }
        #pragma unroll
        for (int nb = 0; nb < 4; ++nb) {
            s16x8 w;
            #pragma unroll
            for (int j = 0; j < 8; ++j) {
                const int kk = (j < 4) ? (lq * 4 + j) : (16 + lq * 4 + (j - 4));
                w[j] = (short)(kk < 16 ? f2bf(Wr[(size_t)kk * 64 + nb * 16 + ln]) : 0);
            }
            wrf[nb] = w;
        }
    }
    __syncthreads();

    const int tiles   = (n_edges + 15) >> 4;
    const int tstride = gridDim.x * 8;
    int T = blockIdx.x * 8 + wave;
    if (T >= tiles) return;

    const int2* nb2 = (const int2*)nbr;

    // ---- prologue: gathers for T; streams for T (cur) and T+s (next) ----
    int Tn = T + tstride;
    bool havenext = (Tn < tiles);
    int2 nbc = nb2[min(T * 16 + n, n_edges - 1)];
    int2 nbn = nbc;
    if (havenext) nbn = nb2[min(Tn * 16 + n, n_edges - 1)];

    s16x8 ai0 = *(const s16x8*)&Af[(size_t)nbc.x * 64 + q * 8];
    s16x8 ai1 = *(const s16x8*)&Af[(size_t)nbc.x * 64 + 32 + q * 8];
    s16x8 aj0 = *(const s16x8*)&Af[(size_t)nbc.y * 64 + q * 8];
    s16x8 aj1 = *(const s16x8*)&Af[(size_t)nbc.y * 64 + 32 + q * 8];

    const int e0 = min(T * 16 + n, n_edges - 1);
    const float* xr0 = edge_ij + (size_t)e0 * 64;
    float4 cx0 = *(const float4*)(xr0 +      q * 4);
    float4 cx1 = *(const float4*)(xr0 + 16 + q * 4);
    float4 cx2 = *(const float4*)(xr0 + 32 + q * 4);
    float4 cx3 = *(const float4*)(xr0 + 48 + q * 4);
    float4 cb  = *(const float4*)(bonds_r + (size_t)e0 * 16 + q * 4);

    const int e1 = havenext ? min(Tn * 16 + n, n_edges - 1) : e0;
    const float* xr1 = edge_ij + (size_t)e1 * 64;
    float4 nx0 = *(const float4*)(xr1 +      q * 4);
    float4 nx1 = *(const float4*)(xr1 + 16 + q * 4);
    float4 nx2 = *(const float4*)(xr1 + 32 + q * 4);
    float4 nx3 = *(const float4*)(xr1 + 48 + q * 4);
    float4 nbd = *(const float4*)(bonds_r + (size_t)e1 * 16 + q * 4);

    while (true) {
        const int E0 = T * 16;

        // ---- pack current streams (cx/cb die here -> free for rotation) --
        s16x8 xf0 = pack8(cx0, cx1);
        s16x8 xf1 = pack8(cx2, cx3);
        s16x8 bfrag;
        {
            union { u32x4 u; s16x8 v; } B;
            B.u[0] = cvtpk(cb.x, cb.y);
            B.u[1] = cvtpk(cb.z, cb.w);
            B.u[2] = 0; B.u[3] = 0;
            bfrag = B.v;
        }

        // ---- acc init = biases ----
        f32x4 acc1[4], acc2[4];
        #pragma unroll
        for (int nb = 0; nb < 4; ++nb) {
            acc1[nb] = *(const f32x4*)&blds[nb * 16 + q * 4];
            acc2[nb] = *(const f32x4*)&blds[64 + nb * 16 + q * 4];
        }

        // ---- layer 1, atom part: kh 0..3 ----
        __builtin_amdgcn_s_setprio(1);
        #pragma unroll
        for (int nb = 0; nb < 4; ++nb) {
            s16x8 w;
            w = *(const s16x8*)&wlds[( 0 + nb) * 512 + lane * 8];
            acc1[nb] = __builtin_amdgcn_mfma_f32_16x16x32_bf16(w, ai0, acc1[nb], 0, 0, 0);
            w = *(const s16x8*)&wlds[( 4 + nb) * 512 + lane * 8];
            acc1[nb] = __builtin_amdgcn_mfma_f32_16x16x32_bf16(w, ai1, acc1[nb], 0, 0, 0);
            w = *(const s16x8*)&wlds[( 8 + nb) * 512 + lane * 8];
            acc1[nb] = __builtin_amdgcn_mfma_f32_16x16x32_bf16(w, aj0, acc1[nb], 0, 0, 0);
            w = *(const s16x8*)&wlds[(12 + nb) * 512 + lane * 8];
            acc1[nb] = __builtin_amdgcn_mfma_f32_16x16x32_bf16(w, aj1, acc1[nb], 0, 0, 0);
            w = *(const s16x8*)&wlds[(24 + nb) * 512 + lane * 8];
            acc2[nb] = __builtin_amdgcn_mfma_f32_16x16x32_bf16(w, ai0, acc2[nb], 0, 0, 0);
            w = *(const s16x8*)&wlds[(28 + nb) * 512 + lane * 8];
            acc2[nb] = __builtin_amdgcn_mfma_f32_16x16x32_bf16(w, ai1, acc2[nb], 0, 0, 0);
            w = *(const s16x8*)&wlds[(32 + nb) * 512 + lane * 8];
            acc2[nb] = __builtin_amdgcn_mfma_f32_16x16x32_bf16(w, aj0, acc2[nb], 0, 0, 0);
            w = *(const s16x8*)&wlds[(36 + nb) * 512 + lane * 8];
            acc2[nb] = __builtin_amdgcn_mfma_f32_16x16x32_bf16(w, aj1, acc2[nb], 0, 0, 0);
        }
        __builtin_amdgcn_s_setprio(0);

        // ---- prefetch: gathers for T+1 (depth-1); streams rotate to
        //      depth-2 — copy next->cur, then issue T+2 into next ----
        const int T2 = Tn + tstride;
        const bool haveT2 = (T2 < tiles);
        s16x8 nai0 = ai0, nai1 = ai1, naj0 = aj0, naj1 = aj1;
        if (havenext) {
            nai0 = *(const s16x8*)&Af[(size_t)nbn.x * 64 + q * 8];
            nai1 = *(const s16x8*)&Af[(size_t)nbn.x * 64 + 32 + q * 8];
            naj0 = *(const s16x8*)&Af[(size_t)nbn.y * 64 + q * 8];
            naj1 = *(const s16x8*)&Af[(size_t)nbn.y * 64 + 32 + q * 8];
            if (haveT2) nbn = nb2[min(T2 * 16 + n, n_edges - 1)];
        }
        // rotate streams (cx dead since pack8): cur <- next
        cx0 = nx0; cx1 = nx1; cx2 = nx2; cx3 = nx3; cb = nbd;
        if (haveT2) {
            const int e2 = min(T2 * 16 + n, n_edges - 1);
            const float* xr2 = edge_ij + (size_t)e2 * 64;
            nx0 = *(const float4*)(xr2 +      q * 4);
            nx1 = *(const float4*)(xr2 + 16 + q * 4);
            nx2 = *(const float4*)(xr2 + 32 + q * 4);
            nx3 = *(const float4*)(xr2 + 48 + q * 4);
            nbd = *(const float4*)(bonds_r + (size_t)e2 * 16 + q * 4);
        }

        // ---- layer 1, e_ij part: kh 4..5 ----
        __builtin_amdgcn_s_setprio(1);
        #pragma unroll
        for (int nb = 0; nb < 4; ++nb) {
            s16x8 w;
            w = *(const s16x8*)&wlds[(16 + nb) * 512 + lane * 8];
            acc1[nb] = __builtin_amdgcn_mfma_f32_16x16x32_bf16(w, xf0, acc1[nb], 0, 0, 0);
            w = *(const s16x8*)&wlds[(20 + nb) * 512 + lane * 8];
            acc1[nb] = __builtin_amdgcn_mfma_f32_16x16x32_bf16(w, xf1, acc1[nb], 0, 0, 0);
            acc2[nb] = __builtin_amdgcn_mfma_f32_16x16x32_bf16(w2e[nb],     xf0, acc2[nb], 0, 0, 0);
            acc2[nb] = __builtin_amdgcn_mfma_f32_16x16x32_bf16(w2e[4 + nb], xf1, acc2[nb], 0, 0, 0);
        }
        __builtin_amdgcn_s_setprio(0);

        // ---- h lane-local, merged rcp: a1*rcp((1+e^-a1)(1+e^-a2)) ----
        f32x4 h[4];
        #pragma unroll
        for (int nb = 0; nb < 4; ++nb) {
            f32x4 s1 = acc1[nb], s2 = acc2[nb], hv;
            #pragma unroll
            for (int j = 0; j < 4; ++j) {
                float ea = __expf(-s1[j]);
                float eb = __expf(-s2[j]);
                hv[j] = s1[j] * __builtin_amdgcn_rcpf((1.0f + ea) * (1.0f + eb));
            }
            h[nb] = hv;
        }
        s16x8 hf0, hf1;
        {
            union { u32x4 u; s16x8 v; } H0, H1;
            H0.u[0] = cvtpk(h[0][0], h[0][1]);
            H0.u[1] = cvtpk(h[0][2], h[0][3]);
            H0.u[2] = cvtpk(h[1][0], h[1][1]);
            H0.u[3] = cvtpk(h[1][2], h[1][3]);
            H1.u[0] = cvtpk(h[2][0], h[2][1]);
            H1.u[1] = cvtpk(h[2][2], h[2][3]);
            H1.u[2] = cvtpk(h[3][0], h[3][1]);
            H1.u[3] = cvtpk(h[3][2], h[3][3]);
            hf0 = H0.v; hf1 = H1.v;
        }

        // ---- layer 2 (h @ W3) and gate (bonds @ Wr): register weights ----
        f32x4 a3[4], g[4];
        #pragma unroll
        for (int nb = 0; nb < 4; ++nb) { a3[nb] = (f32x4){0,0,0,0}; g[nb] = (f32x4){0,0,0,0}; }
        __builtin_amdgcn_s_setprio(1);
        #pragma unroll
        for (int nb = 0; nb < 4; ++nb) {
            a3[nb] = __builtin_amdgcn_mfma_f32_16x16x32_bf16(hf0, w3f[nb],     a3[nb], 0, 0, 0);
            a3[nb] = __builtin_amdgcn_mfma_f32_16x16x32_bf16(hf1, w3f[4 + nb], a3[nb], 0, 0, 0);
            g[nb]  = __builtin_amdgcn_mfma_f32_16x16x32_bf16(bfrag, wrf[nb],   g[nb],  0, 0, 0);
        }
        __builtin_amdgcn_s_setprio(0);

        // ---- out[edge q*4+j][oc nb*16+n] = silu(a3+b3)*(g+br) ----
        float* outp = out + (size_t)(E0 + q * 4) * 64 + n;
        if (E0 + 16 <= n_edges) {
            #pragma unroll
            for (int nb = 0; nb < 4; ++nb) {
                const float b3s = blds[128 + nb * 16 + n];
                const float brs = blds[192 + nb * 16 + n];
                f32x4 s  = a3[nb] + b3s;
                f32x4 gg = g[nb] + brs;
                f32x4 o;
                #pragma unroll
                for (int j = 0; j < 4; ++j)
                    o[j] = s[j] * sigf(s[j]) * gg[j];
                #pragma unroll
                for (int j = 0; j < 4; ++j)
                    outp[j * 64 + nb * 16] = o[j];
            }
        } else {
            #pragma unroll
            for (int nb = 0; nb < 4; ++nb) {
                const float b3s = blds[128 + nb * 16 + n];
                const float brs = blds[192 + nb * 16 + n];
                f32x4 s  = a3[nb] + b3s;
                f32x4 gg = g[nb] + brs;
                #pragma unroll
                for (int j = 0; j < 4; ++j)
                    if (E0 + q * 4 + j < n_edges)
                        outp[j * 64 + nb * 16] = s[j] * sigf(s[j]) * gg[j];
            }
        }

        if (!havenext) break;
        // ---- advance ----
        T = Tn;
        Tn = T2;
        havenext = (Tn < tiles);
        ai0 = nai0; ai1 = nai1; aj0 = naj0; aj1 = naj1;
    }
}

// ---------------------------------------------------------------------------
extern "C" void kernel_launch(void* const* d_in, const int* in_sizes, int n_in,
                              void* d_out, int out_size, void* d_ws, size_t ws_size,
                              hipStream_t stream) {
    const float* atom_fea = (const float*)d_in[0];
    const float* edge_ij  = (const float*)d_in[1];
    const int*   nbr      = (const int*)  d_in[2];
    const float* bonds_r  = (const float*)d_in[3];
    const float* W1 = (const float*)d_in[4];
    const float* b1 = (const float*)d_in[5];
    const float* W2 = (const float*)d_in[6];
    const float* b2 = (const float*)d_in[7];
    const float* Wr = (const float*)d_in[8];
    const float* br = (const float*)d_in[9];
    const float* W3 = (const float*)d_in[10];
    const float* b3 = (const float*)d_in[11];
    float* out = (float*)d_out;
    unsigned short* Af = (unsigned short*)d_ws;   // 50000*64 bf16 = 6.4 MB

    const int n_atoms = in_sizes[0] / 64;
    const int n_edges = in_sizes[2] / 2;

    hipLaunchKernelGGL(atom_conv_kernel, dim3(2048), dim3(256), 0, stream,
                       atom_fea, Af, n_atoms * 64);

    hipLaunchKernelGGL(edge_kernel, dim3(512), dim3(512), 0, stream,
                       Af, edge_ij, nbr, bonds_r,
                       W1, b1, W2, b2, W3, b3, Wr, br, out, n_edges);
}